// Round 17
// baseline (2213.216 us; speedup 1.0000x reference)
//
#include <hip/hip_runtime.h>
#include <math.h>

#define BATCH   512
#define TSTEPS  3600
#define H       64
#define XCHUNK  8
#define NCHUNK  (TSTEPS / XCHUNK)   // 450
#define CLASSES 5

typedef _Float16 half8 __attribute__((ext_vector_type(8)));
typedef float    f32x4 __attribute__((ext_vector_type(4)));

__device__ __forceinline__ half8 bc_h8(uint4 v) {
    return __builtin_bit_cast(half8, v);
}

__device__ __forceinline__ float fast_sigmoid(float x) {
    float e = __expf(-x);                 // |x| <= ~9 by construction
    return __builtin_amdgcn_rcpf(1.0f + e);
}
__device__ __forceinline__ float fast_tanh(float x) {
    float e = __expf(2.0f * x);           // |2x| <= ~18, no overflow
    return (e - 1.0f) * __builtin_amdgcn_rcpf(e + 1.0f);
}

// TWO BATCHES PER WAVE, R13 MFMA-GEMV per chain, weights SHARED.
// Model (fit over R6..R16): a lone wave issues max 1 instr / 4 cyc (GCN
// slot cadence). R13's step = ~56 instrs (~224 cyc issue) but 726 cyc wall
// -> ~500 cyc is exposed latency (LDS RT + MFMA dep chains + transcendental
// tail). Pairing two independent chains in ONE wave doubles issue (~480)
// but overlaps the latency: pair wall ~ max(480, 726+eps) ~ 800 per TWO
// steps. R11 failed at this because its dot2 step was ISSUE-dominated
// (~250 instrs -> 2x issue = 2x wall, no spill - WRITE_SIZE showed none);
// the MFMA step is latency-dominated, the favorable case. And unlike R11,
// the big register consumer (wB = 48 VGPRs) is SHARED by both chains.
// Per-chain A-build stays R13's LDS path (beat bpermute in R16): private
// hl buffer each, one asm clobber orders both publishes before both reads
// (TBAA fix). 6 DS ops per pair - DS pipe trivial. Tiles and gate tails
// interleaved A/B so the scheduler can mesh the two dependency chains.
__global__ __launch_bounds__(64, 1) void gru_mfma_x2_kernel(
    const float* __restrict__ x,      // [B, T, 1]
    const float* __restrict__ w_ih,   // [192, 1]
    const float* __restrict__ w_hh,   // [192, 64]
    const float* __restrict__ b_ih,   // [192]
    const float* __restrict__ b_hh,   // [192]
    const float* __restrict__ w_head, // [5, 64]
    const float* __restrict__ b_head, // [5]
    float* __restrict__ out)          // [B, 5]
{
    __shared__ __align__(16) _Float16 hlA[H];
    __shared__ __align__(16) _Float16 hlB[H];

    const int lane = threadIdx.x;    // block = 1 wave
    const int bA   = 2 * blockIdx.x;
    const int bB   = bA + 1;
    const int q    = lane >> 4;      // k-octet / row-tile selector
    const int col  = lane & 15;      // B n-index / D col

    // --- B fragments (SHARED): B[k=8q+j][n=col] = W[16t+col][32c+8q+j] ---
    half8 wB[12][2];
#pragma unroll
    for (int t = 0; t < 12; ++t) {
#pragma unroll
        for (int c = 0; c < 2; ++c) {
            const float* wr = w_hh + (16 * t + col) * H + 32 * c + 8 * q;
            half8 f;
#pragma unroll
            for (int j = 0; j < 8; ++j) f[j] = (_Float16)wr[j];
            wB[t][c] = f;
        }
    }

    // gate parameters for hidden index = lane (shared by both chains)
    const float wih_r = w_ih[lane], wih_z = w_ih[H + lane], wih_n = w_ih[2 * H + lane];
    const float bsr = b_ih[lane] + b_hh[lane];
    const float bsz = b_ih[H + lane] + b_hh[H + lane];
    const float bin = b_ih[2 * H + lane];
    const float bhn = b_hh[2 * H + lane];

    float hA = 0.0f, hB = 0.0f;
    const float* xbA = x + (size_t)bA * TSTEPS;
    const float* xbB = x + (size_t)bB * TSTEPS;

    // deterministic LDS start state
    hlA[lane] = (_Float16)0.0f;
    hlB[lane] = (_Float16)0.0f;
    __asm volatile("" ::: "memory");

    const f32x4 Z = {0.f, 0.f, 0.f, 0.f};

    // x double-buffers
    float xcA[XCHUNK], xnA[XCHUNK], xcB[XCHUNK], xnB[XCHUNK];
#pragma unroll
    for (int k = 0; k < XCHUNK; ++k) { xcA[k] = xbA[k]; xcB[k] = xbB[k]; }

    for (int tc = 0; tc < NCHUNK; ++tc) {
        const int noff = (tc + 1 < NCHUNK) ? (tc + 1) * XCHUNK : 0;
#pragma unroll
        for (int k = 0; k < XCHUNK; ++k) { xnA[k] = xbA[noff + k]; xnB[k] = xbB[noff + k]; }

#pragma unroll
        for (int tt = 0; tt < XCHUNK; ++tt) {
            // publish both h's; single clobber orders both stores before loads
            hlA[lane] = (_Float16)hA;
            hlB[lane] = (_Float16)hB;
            __asm volatile("" ::: "memory");

            const uint4* hpA = (const uint4*)hlA;
            const uint4* hpB = (const uint4*)hlB;
            const half8 A0A = bc_h8(hpA[q]);      // k = 8q..8q+7
            const half8 A1A = bc_h8(hpA[4 + q]);  // k = 32+8q..
            const half8 A0B = bc_h8(hpB[q]);
            const half8 A1B = bc_h8(hpB[4 + q]);

            const float xtA = xcA[tt], xtB = xcB[tt];
            const float irA = fmaf(xtA, wih_r, bsr), irB = fmaf(xtB, wih_r, bsr);
            const float izA = fmaf(xtA, wih_z, bsz), izB = fmaf(xtB, wih_z, bsz);
            const float inA = fmaf(xtA, wih_n, bin), inB = fmaf(xtB, wih_n, bin);

#define GEMV(A0, A1, t, d)                                                    \
            d = __builtin_amdgcn_mfma_f32_16x16x32_f16(A0, wB[t][0], Z, 0, 0, 0); \
            d = __builtin_amdgcn_mfma_f32_16x16x32_f16(A1, wB[t][1], d, 0, 0, 0);
#define SEL(d0, d1, d2, d3)                                                   \
            ((q < 2) ? (q == 0 ? d0[0] : d1[0]) : (q == 2 ? d2[0] : d3[0]))

            // ---- r tiles (A/B interleaved); sigmoids overlap z/n tiles ----
            f32x4 dA0, dA1, dA2, dA3, dB0, dB1, dB2, dB3;
            GEMV(A0A, A1A, 0, dA0) GEMV(A0B, A1B, 0, dB0)
            GEMV(A0A, A1A, 1, dA1) GEMV(A0B, A1B, 1, dB1)
            GEMV(A0A, A1A, 2, dA2) GEMV(A0B, A1B, 2, dB2)
            GEMV(A0A, A1A, 3, dA3) GEMV(A0B, A1B, 3, dB3)
            const float rA = fast_sigmoid(irA + SEL(dA0, dA1, dA2, dA3));
            const float rB = fast_sigmoid(irB + SEL(dB0, dB1, dB2, dB3));

            f32x4 eA0, eA1, eA2, eA3, eB0, eB1, eB2, eB3;
            GEMV(A0A, A1A, 4, eA0) GEMV(A0B, A1B, 4, eB0)
            GEMV(A0A, A1A, 5, eA1) GEMV(A0B, A1B, 5, eB1)
            GEMV(A0A, A1A, 6, eA2) GEMV(A0B, A1B, 6, eB2)
            GEMV(A0A, A1A, 7, eA3) GEMV(A0B, A1B, 7, eB3)
            const float zA = fast_sigmoid(izA + SEL(eA0, eA1, eA2, eA3));
            const float zB = fast_sigmoid(izB + SEL(eB0, eB1, eB2, eB3));

            f32x4 gA0, gA1, gA2, gA3, gB0, gB1, gB2, gB3;
            GEMV(A0A, A1A, 8,  gA0) GEMV(A0B, A1B, 8,  gB0)
            GEMV(A0A, A1A, 9,  gA1) GEMV(A0B, A1B, 9,  gB1)
            GEMV(A0A, A1A, 10, gA2) GEMV(A0B, A1B, 10, gB2)
            GEMV(A0A, A1A, 11, gA3) GEMV(A0B, A1B, 11, gB3)
            const float ghnA = SEL(gA0, gA1, gA2, gA3);
            const float ghnB = SEL(gB0, gB1, gB2, gB3);
#undef SEL
#undef GEMV

            const float nA = fast_tanh(inA + rA * (ghnA + bhn));
            const float nB = fast_tanh(inB + rB * (ghnB + bhn));
            hA = fmaf(zA, hA - nA, nA);
            hB = fmaf(zB, hB - nB, nB);
        }

#pragma unroll
        for (int k = 0; k < XCHUNK; ++k) { xcA[k] = xnA[k]; xcB[k] = xnB[k]; }
    }

    // ---- head for both batches ----
#pragma unroll
    for (int cc = 0; cc < CLASSES; ++cc) {
        float vA = hA * w_head[cc * H + lane];
        float vB = hB * w_head[cc * H + lane];
#pragma unroll
        for (int off = 32; off > 0; off >>= 1) {
            vA += __shfl_down(vA, off, 64);
            vB += __shfl_down(vB, off, 64);
        }
        if (lane == 0) {
            out[bA * CLASSES + cc] = vA + b_head[cc];
            out[bB * CLASSES + cc] = vB + b_head[cc];
        }
    }
}

extern "C" void kernel_launch(void* const* d_in, const int* in_sizes, int n_in,
                              void* d_out, int out_size, void* d_ws, size_t ws_size,
                              hipStream_t stream) {
    const float* x      = (const float*)d_in[0];
    const float* w_ih   = (const float*)d_in[1];
    const float* w_hh   = (const float*)d_in[2];
    const float* b_ih   = (const float*)d_in[3];
    const float* b_hh   = (const float*)d_in[4];
    const float* w_head = (const float*)d_in[5];
    const float* b_head = (const float*)d_in[6];
    float* out = (float*)d_out;

    gru_mfma_x2_kernel<<<BATCH / 2, 64, 0, stream>>>(x, w_ih, w_hh, b_ih, b_hh,
                                                     w_head, b_head, out);
}

// Round 18
// 1447.157 us; speedup vs baseline: 1.5294x; 1.5294x over previous
//
#include <hip/hip_runtime.h>
#include <math.h>

#define BATCH   512
#define TSTEPS  3600
#define H       64
#define XCHUNK  16
#define NCHUNK  (TSTEPS / XCHUNK)   // 225
#define CLASSES 5

typedef _Float16 half8 __attribute__((ext_vector_type(8)));
typedef _Float16 h2    __attribute__((ext_vector_type(2)));
typedef float    f32x4 __attribute__((ext_vector_type(4)));

__device__ __forceinline__ half8 bc_h8(uint4 v) { return __builtin_bit_cast(half8, v); }
__device__ __forceinline__ h2    bc_h2(unsigned int v) { return __builtin_bit_cast(h2, v); }

__device__ __forceinline__ float fast_sigmoid(float x) {
    float e = __expf(-x);                 // |x| <= ~9 by construction
    return __builtin_amdgcn_rcpf(1.0f + e);
}
__device__ __forceinline__ float fast_tanh(float x) {
    float e = __expf(2.0f * x);           // |2x| <= ~18, no overflow
    return (e - 1.0f) * __builtin_amdgcn_rcpf(e + 1.0f);
}

// ONE WAVE per batch, PIPE-SPLIT dot: r,z gates on the MFMA pipe (16
// v_mfma_f32_16x16x32_f16, ~256 cyc matrix-pipe occupancy), n gate on the
// VALU pipe (32 v_dot2_f32_f16, ~128 cyc) issued in the MFMA shadow. R17
// proved per-wave work on ONE pipe serializes (2 chains = 2x wall); this
// tests the cross-pipe split: matrix + vector pipes co-schedule (m114).
// n lands directly at hidden=lane (no cndmask extraction) and is ready
// before r's sigmoid -> tail chain = SELr -> sigmoid -> r*(ghn+bhn) ->
// tanh -> update. h published once as f16; A-frags (2 b128) + dot2 pairs
// (8 b128) read from the same buffer; TBAA clobber pins order. MFMA
// formulation for r,z identical to validated R13 (tiles t=0..7).
__global__ __launch_bounds__(64, 1) void gru_hybrid_kernel(
    const float* __restrict__ x,      // [B, T, 1]
    const float* __restrict__ w_ih,   // [192, 1]
    const float* __restrict__ w_hh,   // [192, 64]
    const float* __restrict__ b_ih,   // [192]
    const float* __restrict__ b_hh,   // [192]
    const float* __restrict__ w_head, // [5, 64]
    const float* __restrict__ b_head, // [5]
    float* __restrict__ out)          // [B, 5]
{
    __shared__ __align__(16) _Float16 hl[H];

    const int lane = threadIdx.x;    // block = 1 wave
    const int b    = blockIdx.x;
    const int q    = lane >> 4;      // k-octet / row-tile selector
    const int col  = lane & 15;      // B n-index / D col

    // --- B fragments for r,z: tiles t=0..7 (0-3 r, 4-7 z) ---
    half8 wB[8][2];
#pragma unroll
    for (int t = 0; t < 8; ++t) {
#pragma unroll
        for (int c = 0; c < 2; ++c) {
            const float* wr = w_hh + (16 * t + col) * H + 32 * c + 8 * q;
            half8 f;
#pragma unroll
            for (int j = 0; j < 8; ++j) f[j] = (_Float16)wr[j];
            wB[t][c] = f;
        }
    }

    // --- n-gate weights as f16 pairs for v_dot2: row 128+lane ---
    const float* rn = w_hh + (2 * H + lane) * H;
    h2 wn[32];
#pragma unroll
    for (int u = 0; u < 32; ++u)
        wn[u] = (h2){(_Float16)rn[2 * u], (_Float16)rn[2 * u + 1]};

    // gate parameters for hidden index = lane
    const float wih_r = w_ih[lane], wih_z = w_ih[H + lane], wih_n = w_ih[2 * H + lane];
    const float bsr = b_ih[lane] + b_hh[lane];
    const float bsz = b_ih[H + lane] + b_hh[H + lane];
    const float bin = b_ih[2 * H + lane];
    const float bhn = b_hh[2 * H + lane];

    float h_reg = 0.0f;
    const float* xb = x + (size_t)b * TSTEPS;

    hl[lane] = (_Float16)0.0f;
    __asm volatile("" ::: "memory");

    const f32x4 Z = {0.f, 0.f, 0.f, 0.f};

    float xc[XCHUNK], xn[XCHUNK];
#pragma unroll
    for (int k = 0; k < XCHUNK; ++k) xc[k] = xb[k];

    for (int tc = 0; tc < NCHUNK; ++tc) {
        const float* nb = xb + ((tc + 1 < NCHUNK) ? (tc + 1) * XCHUNK : 0);
#pragma unroll
        for (int k = 0; k < XCHUNK; ++k) xn[k] = nb[k];

#pragma unroll
        for (int tt = 0; tt < XCHUNK; ++tt) {
            hl[lane] = (_Float16)h_reg;
            __asm volatile("" ::: "memory");

            const uint4* hp = (const uint4*)hl;
            // A-fragments for the MFMAs
            const half8 A0 = bc_h8(hp[q]);        // k = 8q..8q+7
            const half8 A1 = bc_h8(hp[4 + q]);    // k = 32+8q..
            // pair quads for the n-gate dot2 stream
            const uint4 q0 = hp[0], q1 = hp[1], q2 = hp[2], q3 = hp[3];
            const uint4 q4 = hp[4], q5 = hp[5], q6 = hp[6], q7 = hp[7];

            const float xt = xc[tt];
            const float ir = fmaf(xt, wih_r, bsr);
            const float iz = fmaf(xt, wih_z, bsz);
            const float in_ = fmaf(xt, wih_n, bin);

#define GEMV(t, d)                                                     \
            d = __builtin_amdgcn_mfma_f32_16x16x32_f16(A0, wB[t][0], Z, 0, 0, 0); \
            d = __builtin_amdgcn_mfma_f32_16x16x32_f16(A1, wB[t][1], d, 0, 0, 0);
#define RND4(u, Q)                                                          \
            an0 = __builtin_amdgcn_fdot2(wn[u + 0], bc_h2((Q).x), an0, false); \
            an1 = __builtin_amdgcn_fdot2(wn[u + 1], bc_h2((Q).y), an1, false); \
            an0 = __builtin_amdgcn_fdot2(wn[u + 2], bc_h2((Q).z), an0, false); \
            an1 = __builtin_amdgcn_fdot2(wn[u + 3], bc_h2((Q).w), an1, false);

            float an0 = bhn, an1 = 0.f;
            // interleave: MFMA bursts (matrix pipe) + dot2 (VALU pipe)
            f32x4 d0, d1, d2, d3;           // r tiles
            GEMV(0, d0) RND4(0,  q0)
            GEMV(1, d1) RND4(4,  q1)
            GEMV(2, d2) RND4(8,  q2)
            GEMV(3, d3) RND4(12, q3)
            f32x4 e0, e1, e2, e3;           // z tiles
            GEMV(4, e0) RND4(16, q4)
            GEMV(5, e1) RND4(20, q5)
            GEMV(6, e2) RND4(24, q6)
            GEMV(7, e3) RND4(28, q7)
#undef RND4
#undef GEMV

            const float ghn = an0 + an1;    // ready before the MFMAs drain
            const float ghr = (q < 2) ? (q == 0 ? d0[0] : d1[0])
                                      : (q == 2 ? d2[0] : d3[0]);
            const float r = fast_sigmoid(ir + ghr);
            const float ghz = (q < 2) ? (q == 0 ? e0[0] : e1[0])
                                      : (q == 2 ? e2[0] : e3[0]);
            const float z = fast_sigmoid(iz + ghz);
            const float n = fast_tanh(in_ + r * ghn);
            h_reg = fmaf(z, h_reg - n, n);   // (1-z)*n + z*h
        }

#pragma unroll
        for (int k = 0; k < XCHUNK; ++k) xc[k] = xn[k];
    }

    // ---- head: out[b][c] = w_head[c,:] . h + b_head[c] ----
#pragma unroll
    for (int cc = 0; cc < CLASSES; ++cc) {
        float v = h_reg * w_head[cc * H + lane];
#pragma unroll
        for (int off = 32; off > 0; off >>= 1)
            v += __shfl_down(v, off, 64);
        if (lane == 0) out[b * CLASSES + cc] = v + b_head[cc];
    }
}

extern "C" void kernel_launch(void* const* d_in, const int* in_sizes, int n_in,
                              void* d_out, int out_size, void* d_ws, size_t ws_size,
                              hipStream_t stream) {
    const float* x      = (const float*)d_in[0];
    const float* w_ih   = (const float*)d_in[1];
    const float* w_hh   = (const float*)d_in[2];
    const float* b_ih   = (const float*)d_in[3];
    const float* b_hh   = (const float*)d_in[4];
    const float* w_head = (const float*)d_in[5];
    const float* b_head = (const float*)d_in[6];
    float* out = (float*)d_out;

    gru_hybrid_kernel<<<BATCH, 64, 0, stream>>>(x, w_ih, w_hh, b_ih, b_hh,
                                                w_head, b_head, out);
}